// Round 4
// baseline (306.819 us; speedup 1.0000x reference)
//
#include <hip/hip_runtime.h>
#include <math.h>
#include <stdint.h>

// Problem: B=8, N=1024, ME=1024, D=1024, fp32 in/out.
// a = sigmoid(z @ M @ e^T); A = softmax(a, axis=N); e_out = A @ e.
// Outputs concatenated: e_out [B,N,D] then A [B,N,ME].
//
// Fast path: split-bf16 MFMA (x = hi+lo; hi*hi + hi*lo + lo*hi in fp32 MFMA).
// Round 4: 512-thread blocks (8 waves, 32x64 wave-tile). Grid is fixed at 512
// blocks = 2 blocks/CU; 4-wave blocks gave only 2 waves/SIMD (Occupancy 17%,
// MfmaUtil 30%). 8-wave blocks double resident waves per CU.

typedef __bf16 bf16_8 __attribute__((ext_vector_type(8)));
typedef __bf16 bf16_4 __attribute__((ext_vector_type(4)));
typedef float  f32_4  __attribute__((ext_vector_type(4)));

// ---------------------------------------------------------------------------
__device__ __forceinline__ void gload_lds16(const __bf16* g, __bf16* l) {
    __builtin_amdgcn_global_load_lds(
        (const __attribute__((address_space(1))) void*)g,
        (__attribute__((address_space(3))) void*)l,
        16, 0, 0);
}

__device__ __forceinline__ int swz(int r) { return (r ^ (r >> 2)) & 3; }

// Stage a 128x32 bf16 tile into LDS (row-major 32 bf16/row, XOR k-chunk swizzle).
// 512 threads: one 16B global_load_lds per thread. Wave w stages rows w*16..w*16+15.
__device__ __forceinline__ void stage_tile(const __bf16* __restrict__ g, int ldK,
                                           int k0, __bf16* lds, int w, int lane) {
    const int row = w * 16 + (lane >> 2);
    const int kq  = (lane & 3) ^ swz(row);
    gload_lds16(g + (long long)row * ldK + k0 + kq * 8, lds + w * 16 * 32);
}

// NT GEMM: C[Mrows x Ncols] = A[Mrows x K] * B[Ncols x K]^T, bf16 in, fp32 acc.
// 128x128 tile, 8 waves, wave-tile 32x64.
// SPLIT=1: hi/lo inputs, 3 MFMAs per tile-pair.
// EPI 0: store fp32. EPI 1: store exp(sigmoid(x)) fp32 + fused column-sum atomics.
// EPI 2: store hi/lo bf16.
template<int SPLIT, int EPI>
__global__ __launch_bounds__(512, 4) void mfma_gemm_nt(
    const __bf16* __restrict__ Ahi, const __bf16* __restrict__ Alo,
    const __bf16* __restrict__ Bhi, const __bf16* __restrict__ Blo,
    float* __restrict__ C, __bf16* __restrict__ Chi, __bf16* __restrict__ Clo,
    float* __restrict__ sums,
    long long sA, long long sB, long long sC, int Ncols, int K)
{
    __shared__ __bf16 sAh[128 * 32];
    __shared__ __bf16 sBh[128 * 32];
    __shared__ __bf16 sAl[128 * 32];
    __shared__ __bf16 sBl[128 * 32];

    const int tid  = threadIdx.x;
    const int lane = tid & 63;
    const int w    = tid >> 6;          // 0..7
    const long long bz = blockIdx.z;

    const __bf16* pAh = Ahi + bz * sA + (long long)(blockIdx.y * 128) * K;
    const __bf16* pBh = Bhi + bz * sB + (long long)(blockIdx.x * 128) * K;
    const __bf16* pAl = SPLIT ? (Alo + bz * sA + (long long)(blockIdx.y * 128) * K) : nullptr;
    const __bf16* pBl = SPLIT ? (Blo + bz * sB + (long long)(blockIdx.x * 128) * K) : nullptr;

    const int fr = lane & 15;   // fragment row/col within 16
    const int q  = lane >> 4;   // k-quad 0..3
    const int wr = (w >> 1) * 32;   // 4 row groups of 32
    const int wc = (w & 1) * 64;    // 2 col groups of 64

    f32_4 acc[2][4];
#pragma unroll
    for (int i = 0; i < 2; ++i)
#pragma unroll
        for (int j = 0; j < 4; ++j) acc[i][j] = (f32_4){0.f, 0.f, 0.f, 0.f};

    for (int k0 = 0; k0 < K; k0 += 32) {
        stage_tile(pAh, K, k0, sAh, w, lane);
        stage_tile(pBh, K, k0, sBh, w, lane);
        if (SPLIT) {
            stage_tile(pAl, K, k0, sAl, w, lane);
            stage_tile(pBl, K, k0, sBl, w, lane);
        }
        __syncthreads();

        bf16_8 ah[2], al[2], bh[4], bl[4];
#pragma unroll
        for (int i = 0; i < 2; ++i) {
            const int r = wr + 16 * i + fr;
            const int offA = r * 32 + ((q ^ swz(r)) * 8);
            ah[i] = *(const bf16_8*)(sAh + offA);
            if (SPLIT) al[i] = *(const bf16_8*)(sAl + offA);
        }
#pragma unroll
        for (int j = 0; j < 4; ++j) {
            const int c = wc + 16 * j + fr;
            const int offB = c * 32 + ((q ^ swz(c)) * 8);
            bh[j] = *(const bf16_8*)(sBh + offB);
            if (SPLIT) bl[j] = *(const bf16_8*)(sBl + offB);
        }
#pragma unroll
        for (int i = 0; i < 2; ++i)
#pragma unroll
            for (int j = 0; j < 4; ++j) {
                acc[i][j] = __builtin_amdgcn_mfma_f32_16x16x32_bf16(ah[i], bh[j], acc[i][j], 0, 0, 0);
                if (SPLIT) {
                    acc[i][j] = __builtin_amdgcn_mfma_f32_16x16x32_bf16(ah[i], bl[j], acc[i][j], 0, 0, 0);
                    acc[i][j] = __builtin_amdgcn_mfma_f32_16x16x32_bf16(al[i], bh[j], acc[i][j], 0, 0, 0);
                }
            }
        __syncthreads();
    }

    // Epilogue. C/D layout (16x16x32): col = lane&15, row = (lane>>4)*4 + reg.
    const int row0 = blockIdx.y * 128 + wr;
    const int col0 = blockIdx.x * 128 + wc;
    float cs[4] = {0.f, 0.f, 0.f, 0.f};
#pragma unroll
    for (int i = 0; i < 2; ++i)
#pragma unroll
        for (int j = 0; j < 4; ++j) {
            const int col = col0 + 16 * j + fr;
#pragma unroll
            for (int reg = 0; reg < 4; ++reg) {
                const int row = row0 + 16 * i + q * 4 + reg;
                float v = acc[i][j][reg];
                const long long idx = bz * sC + (long long)row * Ncols + col;
                if (EPI == 0) {
                    C[idx] = v;
                } else if (EPI == 1) {
                    float s = 1.0f / (1.0f + __expf(-v));
                    v = __expf(s);
                    C[idx] = v;
                    cs[j] += v;
                } else {
                    __bf16 h = (__bf16)v;
                    Chi[idx] = h;
                    Clo[idx] = (__bf16)(v - (float)h);
                }
            }
        }
    if (EPI == 1) {
        // Reduce column partials across the 4 k-quads (lanes fr, fr+16, fr+32, fr+48).
#pragma unroll
        for (int j = 0; j < 4; ++j) {
            float s = cs[j];
            s += __shfl_xor(s, 16, 64);
            s += __shfl_xor(s, 32, 64);
            if (lane < 16)
                atomicAdd(&sums[bz * Ncols + col0 + 16 * j + lane], s);
        }
    }
}

// x -> hi = bf16(x), lo = bf16(x - hi); float4 per thread.
__global__ __launch_bounds__(256) void split2_kernel(
    const float* __restrict__ x, __bf16* __restrict__ hi, __bf16* __restrict__ lo)
{
    const long long i = (blockIdx.x * 256LL + threadIdx.x) * 4;
    float4 v = *(const float4*)(x + i);
    bf16_4 h, l;
    h[0] = (__bf16)v.x; l[0] = (__bf16)(v.x - (float)h[0]);
    h[1] = (__bf16)v.y; l[1] = (__bf16)(v.y - (float)h[1]);
    h[2] = (__bf16)v.z; l[2] = (__bf16)(v.z - (float)h[2]);
    h[3] = (__bf16)v.w; l[3] = (__bf16)(v.w - (float)h[3]);
    *(bf16_4*)(hi + i) = h;
    *(bf16_4*)(lo + i) = l;
}

// Fused: e [B,ME,D] fp32 -> e_hi,e_lo [B,ME,D] bf16 (row-major) AND eT [B,D,ME] bf16.
__global__ __launch_bounds__(256) void splitT_e_kernel(
    const float* __restrict__ e, __bf16* __restrict__ hi, __bf16* __restrict__ lo,
    __bf16* __restrict__ eT, int ME, int D)
{
    __shared__ float t[64][65];
    const long long bb = blockIdx.z;
    const int m0 = blockIdx.y * 64, d0 = blockIdx.x * 64;
    const int tx = threadIdx.x & 15, ty = threadIdx.x >> 4;   // ty 0..15
#pragma unroll
    for (int i = 0; i < 4; ++i) {
        const int r = 16 * i + ty;
        const long long o = (bb * ME + m0 + r) * (long long)D + d0 + 4 * tx;
        float4 v = *(const float4*)(e + o);
        bf16_4 h, l;
        h[0] = (__bf16)v.x; l[0] = (__bf16)(v.x - (float)h[0]);
        h[1] = (__bf16)v.y; l[1] = (__bf16)(v.y - (float)h[1]);
        h[2] = (__bf16)v.z; l[2] = (__bf16)(v.z - (float)h[2]);
        h[3] = (__bf16)v.w; l[3] = (__bf16)(v.w - (float)h[3]);
        *(bf16_4*)(hi + o) = h;
        *(bf16_4*)(lo + o) = l;
        t[r][4 * tx + 0] = v.x;
        t[r][4 * tx + 1] = v.y;
        t[r][4 * tx + 2] = v.z;
        t[r][4 * tx + 3] = v.w;
    }
    __syncthreads();
#pragma unroll
    for (int i = 0; i < 4; ++i) {
        const int dloc = 16 * i + ty;
        bf16_4 p;
#pragma unroll
        for (int j = 0; j < 4; ++j) p[j] = (__bf16)t[4 * tx + j][dloc];
        const long long o = (bb * D + d0 + dloc) * (long long)ME + m0 + 4 * tx;
        *(bf16_4*)(eT + o) = p;
    }
}

// out[c*R + r] = in[r*C + c] (fp32 in, bf16 hi(+lo) out). Used for M only.
__global__ __launch_bounds__(256) void transpose_split_kernel(
    const float* __restrict__ in, __bf16* __restrict__ hi, __bf16* __restrict__ lo,
    int R, int Cc, int doLo)
{
    __shared__ float t[32][33];
    const long long base = (long long)blockIdx.z * R * Cc;
    const int r0 = blockIdx.y * 32, c0 = blockIdx.x * 32;
    const int tx = threadIdx.x & 31, ty = threadIdx.x >> 5;  // ty 0..7
#pragma unroll
    for (int rr = ty; rr < 32; rr += 8)
        t[rr][tx] = in[base + (long long)(r0 + rr) * Cc + c0 + tx];
    __syncthreads();
#pragma unroll
    for (int cc = ty; cc < 32; cc += 8) {
        const float v = t[tx][cc];
        const long long o = base + (long long)(c0 + cc) * R + r0 + tx;
        __bf16 h = (__bf16)v;
        hi[o] = h;
        if (doLo) lo[o] = (__bf16)(v - (float)h);
    }
}

// P /= colsum, in place; also emit bf16 copy for GEMM3.
__global__ __launch_bounds__(256) void scale2_kernel(
    float* __restrict__ P, const float* __restrict__ sums, __bf16* __restrict__ Pb)
{
    const long long base = (blockIdx.x * 256LL + threadIdx.x) * 4;
    const int b = (int)(base >> 20);
    const int col = (int)(base & 1023);
    float4 v = *(float4*)(P + base);
    const float4 s = *(const float4*)(sums + (b << 10) + col);
    v.x /= s.x; v.y /= s.y; v.z /= s.z; v.w /= s.w;
    *(float4*)(P + base) = v;
    bf16_4 h;
    h[0] = (__bf16)v.x; h[1] = (__bf16)v.y; h[2] = (__bf16)v.z; h[3] = (__bf16)v.w;
    *(bf16_4*)(Pb + base) = h;
}

// ---------------------------------------------------------------------------
// Fallback fp32 path (round-1 kernels).
#define TILE 128
#define KT 8
template<bool BT, int EPI>
__global__ __launch_bounds__(256) void gemm_kernel(
    const float* __restrict__ A, const float* __restrict__ B, float* __restrict__ C,
    long long sA, long long sB, long long sC, int Mrows, int Ncols, int K)
{
    __shared__ float As[KT][TILE + 4];
    __shared__ float Bs[KT][TILE + 4];
    const int bz = blockIdx.z;
    A += (long long)bz * sA; B += (long long)bz * sB; C += (long long)bz * sC;
    const int tid = threadIdx.x;
    const int row0 = blockIdx.y * TILE, col0 = blockIdx.x * TILE;
    const int ld_r = tid >> 1, ld_k4 = (tid & 1) * 4;
    const int bn_k = tid >> 5, bn_c4 = (tid & 31) * 4;
    const int tx = tid & 15, ty = tid >> 4;
    const int c0 = tx * 4, c1 = c0 + 64, r0 = ty * 4, r1 = r0 + 64;
    float acc[8][8];
#pragma unroll
    for (int i = 0; i < 8; i++)
#pragma unroll
        for (int j = 0; j < 8; j++) acc[i][j] = 0.f;
    for (int k0 = 0; k0 < K; k0 += KT) {
        float4 av = *(const float4*)(A + (long long)(row0 + ld_r) * K + k0 + ld_k4);
        float4 bv;
        if (BT) bv = *(const float4*)(B + (long long)(col0 + ld_r) * K + k0 + ld_k4);
        else    bv = *(const float4*)(B + (long long)(k0 + bn_k) * Ncols + col0 + bn_c4);
        __syncthreads();
        As[ld_k4 + 0][ld_r] = av.x; As[ld_k4 + 1][ld_r] = av.y;
        As[ld_k4 + 2][ld_r] = av.z; As[ld_k4 + 3][ld_r] = av.w;
        if (BT) {
            Bs[ld_k4 + 0][ld_r] = bv.x; Bs[ld_k4 + 1][ld_r] = bv.y;
            Bs[ld_k4 + 2][ld_r] = bv.z; Bs[ld_k4 + 3][ld_r] = bv.w;
        } else {
            *(float4*)&Bs[bn_k][bn_c4] = bv;
        }
        __syncthreads();
#pragma unroll
        for (int kk = 0; kk < KT; kk++) {
            float4 a0 = *(const float4*)&As[kk][r0];
            float4 a1 = *(const float4*)&As[kk][r1];
            float4 b0 = *(const float4*)&Bs[kk][c0];
            float4 b1 = *(const float4*)&Bs[kk][c1];
            float ar[8] = {a0.x, a0.y, a0.z, a0.w, a1.x, a1.y, a1.z, a1.w};
            float br[8] = {b0.x, b0.y, b0.z, b0.w, b1.x, b1.y, b1.z, b1.w};
#pragma unroll
            for (int i = 0; i < 8; i++)
#pragma unroll
                for (int j = 0; j < 8; j++) acc[i][j] += ar[i] * br[j];
        }
    }
#pragma unroll
    for (int i = 0; i < 8; i++) {
        const int rr = (i < 4) ? (r0 + i) : (r1 + i - 4);
        float* crow = C + (long long)(row0 + rr) * Ncols + col0;
        float v[8];
#pragma unroll
        for (int j = 0; j < 8; j++) v[j] = acc[i][j];
        if (EPI == 1) {
#pragma unroll
            for (int j = 0; j < 8; j++) {
                float s = 1.0f / (1.0f + __expf(-v[j]));
                v[j] = __expf(s);
            }
        }
        *(float4*)(crow + c0) = make_float4(v[0], v[1], v[2], v[3]);
        *(float4*)(crow + c1) = make_float4(v[4], v[5], v[6], v[7]);
    }
}

__global__ __launch_bounds__(256) void colsum_kernel(
    const float* __restrict__ P, float* __restrict__ sums, int Nn, int Mm, int chunk)
{
    const int g = blockIdx.x * 256 + threadIdx.x;
    const int b = g >> 10;
    const int m = g & 1023;
    const int n0 = blockIdx.y * chunk;
    const float* p = P + (long long)b * Nn * Mm + (long long)n0 * Mm + m;
    float s0 = 0.f, s1 = 0.f, s2 = 0.f, s3 = 0.f;
    for (int n = 0; n < chunk; n += 4) {
        s0 += p[(long long)(n + 0) * Mm];
        s1 += p[(long long)(n + 1) * Mm];
        s2 += p[(long long)(n + 2) * Mm];
        s3 += p[(long long)(n + 3) * Mm];
    }
    atomicAdd(&sums[g], (s0 + s1) + (s2 + s3));
}

__global__ __launch_bounds__(256) void scale_kernel(
    float* __restrict__ P, const float* __restrict__ sums)
{
    const long long base = (blockIdx.x * 256LL + threadIdx.x) * 4;
    const int b = (int)(base >> 20);
    const int col = (int)(base & 1023);
    float4 v = *(float4*)(P + base);
    const float4 s = *(const float4*)(sums + (b << 10) + col);
    v.x /= s.x; v.y /= s.y; v.z /= s.z; v.w /= s.w;
    *(float4*)(P + base) = v;
}

// ---------------------------------------------------------------------------
extern "C" void kernel_launch(void* const* d_in, const int* in_sizes, int n_in,
                              void* d_out, int out_size, void* d_ws, size_t ws_size,
                              hipStream_t stream)
{
    const int B = 8, N = 1024, ME = 1024, D = 1024;
    const float* z = (const float*)d_in[0];   // [B,N,D]
    const float* e = (const float*)d_in[1];   // [B,ME,D]
    const float* M = (const float*)d_in[2];   // [D,D]
    float* out   = (float*)d_out;
    float* e_out = out;                         // [B,N,D]
    float* Aout  = out + (long long)B * N * D;  // [B,N,ME]; holds P then A

    const size_t MB = 1024 * 1024;
    const size_t NEEDED = 100 * MB + (size_t)B * ME * sizeof(float);

    if (ws_size >= NEEDED) {
        char* W = (char*)d_ws;
        __bf16* z_hi  = (__bf16*)(W);
        __bf16* z_lo  = (__bf16*)(W + 16 * MB);
        __bf16* e_hi  = (__bf16*)(W + 32 * MB);
        __bf16* e_lo  = (__bf16*)(W + 48 * MB);
        __bf16* MT_hi = (__bf16*)(W + 64 * MB);
        __bf16* MT_lo = (__bf16*)(W + 66 * MB);
        __bf16* zM_hi = (__bf16*)(W + 68 * MB);
        __bf16* zM_lo = (__bf16*)(W + 84 * MB);
        float*  sums  = (float*)(W + 100 * MB);
        __bf16* A_bf  = z_hi;   // reused after GEMM1 consumes z
        __bf16* eT    = z_lo;   // reused after GEMM1 consumes z

        hipMemsetAsync(sums, 0, (size_t)B * ME * sizeof(float), stream);

        // Prep: z split + M transpose-split.
        split2_kernel<<<dim3((B * N * D / 4) / 256), 256, 0, stream>>>(z, z_hi, z_lo);
        transpose_split_kernel<<<dim3(D / 32, D / 32, 1), 256, 0, stream>>>(
            M, MT_hi, MT_lo, D, D, 1);

        // GEMM1: zM = z @ M  (NT vs M^T), split in + split bf16 out. [8192x1024x1024]
        mfma_gemm_nt<1, 2><<<dim3(D / 128, (B * N) / 128, 1), 512, 0, stream>>>(
            z_hi, z_lo, MT_hi, MT_lo, nullptr, zM_hi, zM_lo, nullptr, 0, 0, 0, D, D);

        // e split (hi/lo) + fused bf16 transpose (eT for GEMM3). z regions now free.
        splitT_e_kernel<<<dim3(D / 64, ME / 64, B), 256, 0, stream>>>(
            e, e_hi, e_lo, eT, ME, D);

        // GEMM2: P = exp(sigmoid(zM @ e^T)), fp32 to Aout, fused column sums.
        mfma_gemm_nt<1, 1><<<dim3(ME / 128, N / 128, B), 512, 0, stream>>>(
            zM_hi, zM_lo, e_hi, e_lo, Aout, nullptr, nullptr, sums,
            (long long)N * D, (long long)ME * D, (long long)N * ME, ME, D);

        // Softmax scale: A = P / colsum (in place) + bf16 A for GEMM3.
        scale2_kernel<<<dim3((B * N * ME / 4) / 256), 256, 0, stream>>>(Aout, sums, A_bf);

        // GEMM3: e_out = A @ e per batch (NT vs eT), plain bf16.
        mfma_gemm_nt<0, 0><<<dim3(D / 128, N / 128, B), 512, 0, stream>>>(
            A_bf, nullptr, eT, nullptr, e_out, nullptr, nullptr, nullptr,
            (long long)N * ME, (long long)D * ME, (long long)N * D, D, ME);
    } else {
        // fp32 fallback (round-1 path), needs 32 MB + 32 KB.
        float* zM   = (float*)d_ws;
        float* sums = (float*)((char*)d_ws + (size_t)B * N * D * 4);
        gemm_kernel<false, 0><<<dim3(ME / TILE, (B * N) / TILE, 1), 256, 0, stream>>>(
            z, M, zM, 0, 0, 0, B * N, D, D);
        gemm_kernel<true, 1><<<dim3(ME / TILE, N / TILE, B), 256, 0, stream>>>(
            zM, e, Aout, (long long)N * D, (long long)ME * D, (long long)N * ME, N, ME, D);
        hipMemsetAsync(sums, 0, (size_t)B * ME * sizeof(float), stream);
        colsum_kernel<<<dim3((B * ME) / 256, 8), 256, 0, stream>>>(Aout, sums, N, ME, N / 8);
        scale_kernel<<<dim3((B * N * ME / 4) / 256), 256, 0, stream>>>(Aout, sums);
        gemm_kernel<false, 0><<<dim3(D / TILE, N / TILE, B), 256, 0, stream>>>(
            Aout, e, e_out, (long long)N * ME, (long long)ME * D, (long long)N * D, N, D, ME);
    }
}

// Round 5
// 276.263 us; speedup vs baseline: 1.1106x; 1.1106x over previous
//
#include <hip/hip_runtime.h>
#include <math.h>
#include <stdint.h>

// Problem: B=8, N=1024, ME=1024, D=1024, fp32 in/out.
// a = sigmoid(z @ M @ e^T); A = softmax(a, axis=N); e_out = A @ e.
// Outputs concatenated: e_out [B,N,D] then A [B,N,ME].
//
// Fast path: split-bf16 MFMA (x = hi+lo; hi*hi + hi*lo + lo*hi in fp32 MFMA).
// Round 5: 5 graph nodes (prep / GEMM1 / GEMM2 / finish / GEMM3); BK=64;
// GEMM2 emits bf16 P directly; softmax normalization folded into GEMM3's B
// operand (e_out = P @ (e/s)); A rebuilt as P_bf/s in finish.

typedef __bf16 bf16_8 __attribute__((ext_vector_type(8)));
typedef __bf16 bf16_4 __attribute__((ext_vector_type(4)));
typedef float  f32_4  __attribute__((ext_vector_type(4)));

// ---------------------------------------------------------------------------
__device__ __forceinline__ void gload_lds16(const __bf16* g, __bf16* l) {
    __builtin_amdgcn_global_load_lds(
        (const __attribute__((address_space(1))) void*)g,
        (__attribute__((address_space(3))) void*)l,
        16, 0, 0);
}

__device__ __forceinline__ int swz(int r) { return (r ^ (r >> 2)) & 3; }

// Stage a 128x64 bf16 tile into LDS. Tile = 128 rows x 8 16B-chunks.
// Chunk layout: row r, chunk slot s holds global chunk (s&4) | ((s^swz(r))&3).
// 256 threads x 4 iters = 1024 chunks; LDS dst is wave-uniform base + lane*16.
__device__ __forceinline__ void stage_tile64(const __bf16* __restrict__ g, int ldK,
                                             int k0, __bf16* lds, int tid) {
#pragma unroll
    for (int t = 0; t < 4; ++t) {
        const int chunk = t * 256 + tid;       // destination chunk index
        const int row = chunk >> 3;
        const int c   = chunk & 7;
        const int csrc = (c & 4) | ((c ^ swz(row)) & 3);
        gload_lds16(g + (long long)row * ldK + k0 + csrc * 8,
                    lds + (t * 256 + (tid >> 6) * 64) * 8);
    }
}

// NT GEMM: C[Mrows x Ncols] = A[Mrows x K] * B[Ncols x K]^T, bf16 in, fp32 acc.
// 128x128 tile, 4 waves, wave-tile 64x64 (4x4 of 16x16), BK=64.
// SPLIT=1: hi/lo inputs, 3 MFMAs per tile-pair.
// EPI 0: store fp32 C. EPI 1: store bf16 Chi + fused column-sum atomics.
// EPI 2: store hi/lo bf16.
template<int SPLIT, int EPI>
__global__ __launch_bounds__(256) void mfma_gemm_nt(
    const __bf16* __restrict__ Ahi, const __bf16* __restrict__ Alo,
    const __bf16* __restrict__ Bhi, const __bf16* __restrict__ Blo,
    float* __restrict__ C, __bf16* __restrict__ Chi, __bf16* __restrict__ Clo,
    float* __restrict__ sums,
    long long sA, long long sB, long long sC, int Ncols, int K)
{
    __shared__ __bf16 smem[(SPLIT ? 4 : 2) * 128 * 64];
    __bf16* sAh = smem;
    __bf16* sBh = smem + 128 * 64;
    __bf16* sAl = SPLIT ? smem + 2 * 128 * 64 : nullptr;
    __bf16* sBl = SPLIT ? smem + 3 * 128 * 64 : nullptr;

    const int tid  = threadIdx.x;
    const int lane = tid & 63;
    const int w    = tid >> 6;          // 0..3
    const long long bz = blockIdx.z;

    const __bf16* pAh = Ahi + bz * sA + (long long)(blockIdx.y * 128) * K;
    const __bf16* pBh = Bhi + bz * sB + (long long)(blockIdx.x * 128) * K;
    const __bf16* pAl = SPLIT ? (Alo + bz * sA + (long long)(blockIdx.y * 128) * K) : nullptr;
    const __bf16* pBl = SPLIT ? (Blo + bz * sB + (long long)(blockIdx.x * 128) * K) : nullptr;

    const int fr = lane & 15;   // fragment row/col within 16
    const int q  = lane >> 4;   // k-quad 0..3
    const int wr = (w >> 1) * 64;
    const int wc = (w & 1) * 64;

    f32_4 acc[4][4];
#pragma unroll
    for (int i = 0; i < 4; ++i)
#pragma unroll
        for (int j = 0; j < 4; ++j) acc[i][j] = (f32_4){0.f, 0.f, 0.f, 0.f};

    for (int k0 = 0; k0 < K; k0 += 64) {
        stage_tile64(pAh, K, k0, sAh, tid);
        stage_tile64(pBh, K, k0, sBh, tid);
        if (SPLIT) {
            stage_tile64(pAl, K, k0, sAl, tid);
            stage_tile64(pBl, K, k0, sBl, tid);
        }
        __syncthreads();

#pragma unroll
        for (int c = 0; c < 2; ++c) {
            bf16_8 ah[4], bh[4], al[4], bl[4];
#pragma unroll
            for (int i = 0; i < 4; ++i) {
                const int r = wr + 16 * i + fr;
                const int offA = (r * 8 + c * 4 + (q ^ swz(r))) * 8;
                ah[i] = *(const bf16_8*)(sAh + offA);
                if (SPLIT) al[i] = *(const bf16_8*)(sAl + offA);
                const int cc = wc + 16 * i + fr;
                const int offB = (cc * 8 + c * 4 + (q ^ swz(cc))) * 8;
                bh[i] = *(const bf16_8*)(sBh + offB);
                if (SPLIT) bl[i] = *(const bf16_8*)(sBl + offB);
            }
#pragma unroll
            for (int i = 0; i < 4; ++i)
#pragma unroll
                for (int j = 0; j < 4; ++j) {
                    acc[i][j] = __builtin_amdgcn_mfma_f32_16x16x32_bf16(ah[i], bh[j], acc[i][j], 0, 0, 0);
                    if (SPLIT) {
                        acc[i][j] = __builtin_amdgcn_mfma_f32_16x16x32_bf16(ah[i], bl[j], acc[i][j], 0, 0, 0);
                        acc[i][j] = __builtin_amdgcn_mfma_f32_16x16x32_bf16(al[i], bh[j], acc[i][j], 0, 0, 0);
                    }
                }
        }
        __syncthreads();
    }

    // Epilogue. C/D layout (16x16x32): col = lane&15, row = (lane>>4)*4 + reg.
    const int row0 = blockIdx.y * 128 + wr;
    const int col0 = blockIdx.x * 128 + wc;
    float cs[4] = {0.f, 0.f, 0.f, 0.f};
#pragma unroll
    for (int i = 0; i < 4; ++i)
#pragma unroll
        for (int j = 0; j < 4; ++j) {
            const int col = col0 + 16 * j + fr;
#pragma unroll
            for (int reg = 0; reg < 4; ++reg) {
                const int row = row0 + 16 * i + q * 4 + reg;
                float v = acc[i][j][reg];
                const long long idx = bz * sC + (long long)row * Ncols + col;
                if (EPI == 0) {
                    C[idx] = v;
                } else if (EPI == 1) {
                    float s = 1.0f / (1.0f + __expf(-v));
                    v = __expf(s);
                    Chi[idx] = (__bf16)v;     // P in bf16 (P in [1,e], rel err 2^-9)
                    cs[j] += v;               // colsum from full-precision v
                } else {
                    __bf16 h = (__bf16)v;
                    Chi[idx] = h;
                    Clo[idx] = (__bf16)(v - (float)h);
                }
            }
        }
    if (EPI == 1) {
        // Reduce column partials across the 4 k-quads (lanes fr, fr+16, fr+32, fr+48).
#pragma unroll
        for (int j = 0; j < 4; ++j) {
            float s = cs[j];
            s += __shfl_xor(s, 16, 64);
            s += __shfl_xor(s, 32, 64);
            if (lane < 16)
                atomicAdd(&sums[bz * Ncols + col0 + 16 * j + lane], s);
        }
    }
}

// ---------------------------------------------------------------------------
// Fused prep: sections by blockIdx.x.
//  [0,8192)       z-split      -> z_hi, z_lo
//  [8192,16384)   e-split      -> e_hi, e_lo
//  [16384,17408)  M transpose-split -> MT_hi, MT_lo
//  [17408,17416)  zero sums (8192 floats)
__global__ __launch_bounds__(256) void prep_kernel(
    const float* __restrict__ z, const float* __restrict__ e, const float* __restrict__ M,
    __bf16* __restrict__ z_hi, __bf16* __restrict__ z_lo,
    __bf16* __restrict__ e_hi, __bf16* __restrict__ e_lo,
    __bf16* __restrict__ MT_hi, __bf16* __restrict__ MT_lo,
    float* __restrict__ sums, int D)
{
    __shared__ float t32[32][33];
    const int bid = blockIdx.x;
    const int tid = threadIdx.x;
    if (bid < 16384) {
        const float* src = (bid < 8192) ? z : e;
        __bf16* hi = (bid < 8192) ? z_hi : e_hi;
        __bf16* lo = (bid < 8192) ? z_lo : e_lo;
        const long long i = (((long long)(bid & 8191)) * 256 + tid) * 4;
        float4 v = *(const float4*)(src + i);
        bf16_4 h, l;
        h[0] = (__bf16)v.x; l[0] = (__bf16)(v.x - (float)h[0]);
        h[1] = (__bf16)v.y; l[1] = (__bf16)(v.y - (float)h[1]);
        h[2] = (__bf16)v.z; l[2] = (__bf16)(v.z - (float)h[2]);
        h[3] = (__bf16)v.w; l[3] = (__bf16)(v.w - (float)h[3]);
        *(bf16_4*)(hi + i) = h;
        *(bf16_4*)(lo + i) = l;
    } else if (bid < 17408) {
        const int t = bid - 16384;
        const int r0 = (t >> 5) * 32, c0 = (t & 31) * 32;
        const int tx = tid & 31, ty = tid >> 5;   // ty 0..7
#pragma unroll
        for (int rr = ty; rr < 32; rr += 8)
            t32[rr][tx] = M[(long long)(r0 + rr) * D + c0 + tx];
        __syncthreads();
#pragma unroll
        for (int cc = ty; cc < 32; cc += 8) {
            const float v = t32[tx][cc];
            const long long o = (long long)(c0 + cc) * D + r0 + tx;
            __bf16 h = (__bf16)v;
            MT_hi[o] = h;
            MT_lo[o] = (__bf16)(v - (float)h);
        }
    } else {
        const int i = ((bid - 17408) * 256 + tid) * 4;
        *(float4*)(sums + i) = make_float4(0.f, 0.f, 0.f, 0.f);
    }
}

// ---------------------------------------------------------------------------
// Fused finish: sections by blockIdx.x.
//  [0,8192)      A fp32 = P_bf / s  (softmax output)
//  [8192,10240)  eTs[b,d,m] = e[b,m,d] / s[b,m]  (bf16, GEMM3 B operand)
__global__ __launch_bounds__(256) void finish_kernel(
    const __bf16* __restrict__ Pb, const float* __restrict__ sums,
    float* __restrict__ A, const float* __restrict__ e, __bf16* __restrict__ eTs,
    int ME, int D)
{
    __shared__ float t64[64][65];
    const int bid = blockIdx.x;
    const int tid = threadIdx.x;
    if (bid < 8192) {
        const long long base = ((long long)bid * 256 + tid) * 4;
        const int b = (int)(base >> 20);
        const int m = (int)(base & 1023);
        const float4 s = *(const float4*)(sums + (b << 10) + m);
        bf16_4 p = *(const bf16_4*)(Pb + base);
        float4 o;
        o.x = (float)p[0] / s.x;
        o.y = (float)p[1] / s.y;
        o.z = (float)p[2] / s.z;
        o.w = (float)p[3] / s.w;
        *(float4*)(A + base) = o;
    } else {
        const int t = bid - 8192;
        const long long bb = t >> 8;
        const int d0 = (t & 15) * 64, m0 = ((t >> 4) & 15) * 64;
        const int tx = tid & 15, ty = tid >> 4;   // ty 0..15
#pragma unroll
        for (int i = 0; i < 4; ++i) {
            const int r = 16 * i + ty;
            float4 v = *(const float4*)(e + (bb * ME + m0 + r) * (long long)D + d0 + 4 * tx);
            t64[r][4 * tx + 0] = v.x;
            t64[r][4 * tx + 1] = v.y;
            t64[r][4 * tx + 2] = v.z;
            t64[r][4 * tx + 3] = v.w;
        }
        __syncthreads();
#pragma unroll
        for (int i = 0; i < 4; ++i) {
            const int dloc = 16 * i + ty;
            bf16_4 p;
#pragma unroll
            for (int j = 0; j < 4; ++j)
                p[j] = (__bf16)(t64[4 * tx + j][dloc] / sums[(bb << 10) + m0 + 4 * tx + j]);
            *(bf16_4*)(eTs + (bb * D + d0 + dloc) * (long long)ME + m0 + 4 * tx) = p;
        }
    }
}

// ---------------------------------------------------------------------------
// Fallback fp32 path (round-1 kernels).
#define TILE 128
#define KT 8
template<bool BT, int EPI>
__global__ __launch_bounds__(256) void gemm_kernel(
    const float* __restrict__ A, const float* __restrict__ B, float* __restrict__ C,
    long long sA, long long sB, long long sC, int Mrows, int Ncols, int K)
{
    __shared__ float As[KT][TILE + 4];
    __shared__ float Bs[KT][TILE + 4];
    const int bz = blockIdx.z;
    A += (long long)bz * sA; B += (long long)bz * sB; C += (long long)bz * sC;
    const int tid = threadIdx.x;
    const int row0 = blockIdx.y * TILE, col0 = blockIdx.x * TILE;
    const int ld_r = tid >> 1, ld_k4 = (tid & 1) * 4;
    const int bn_k = tid >> 5, bn_c4 = (tid & 31) * 4;
    const int tx = tid & 15, ty = tid >> 4;
    const int c0 = tx * 4, c1 = c0 + 64, r0 = ty * 4, r1 = r0 + 64;
    float acc[8][8];
#pragma unroll
    for (int i = 0; i < 8; i++)
#pragma unroll
        for (int j = 0; j < 8; j++) acc[i][j] = 0.f;
    for (int k0 = 0; k0 < K; k0 += KT) {
        float4 av = *(const float4*)(A + (long long)(row0 + ld_r) * K + k0 + ld_k4);
        float4 bv;
        if (BT) bv = *(const float4*)(B + (long long)(col0 + ld_r) * K + k0 + ld_k4);
        else    bv = *(const float4*)(B + (long long)(k0 + bn_k) * Ncols + col0 + bn_c4);
        __syncthreads();
        As[ld_k4 + 0][ld_r] = av.x; As[ld_k4 + 1][ld_r] = av.y;
        As[ld_k4 + 2][ld_r] = av.z; As[ld_k4 + 3][ld_r] = av.w;
        if (BT) {
            Bs[ld_k4 + 0][ld_r] = bv.x; Bs[ld_k4 + 1][ld_r] = bv.y;
            Bs[ld_k4 + 2][ld_r] = bv.z; Bs[ld_k4 + 3][ld_r] = bv.w;
        } else {
            *(float4*)&Bs[bn_k][bn_c4] = bv;
        }
        __syncthreads();
#pragma unroll
        for (int kk = 0; kk < KT; kk++) {
            float4 a0 = *(const float4*)&As[kk][r0];
            float4 a1 = *(const float4*)&As[kk][r1];
            float4 b0 = *(const float4*)&Bs[kk][c0];
            float4 b1 = *(const float4*)&Bs[kk][c1];
            float ar[8] = {a0.x, a0.y, a0.z, a0.w, a1.x, a1.y, a1.z, a1.w};
            float br[8] = {b0.x, b0.y, b0.z, b0.w, b1.x, b1.y, b1.z, b1.w};
#pragma unroll
            for (int i = 0; i < 8; i++)
#pragma unroll
                for (int j = 0; j < 8; j++) acc[i][j] += ar[i] * br[j];
        }
    }
#pragma unroll
    for (int i = 0; i < 8; i++) {
        const int rr = (i < 4) ? (r0 + i) : (r1 + i - 4);
        float* crow = C + (long long)(row0 + rr) * Ncols + col0;
        float v[8];
#pragma unroll
        for (int j = 0; j < 8; j++) v[j] = acc[i][j];
        if (EPI == 1) {
#pragma unroll
            for (int j = 0; j < 8; j++) {
                float s = 1.0f / (1.0f + __expf(-v[j]));
                v[j] = __expf(s);
            }
        }
        *(float4*)(crow + c0) = make_float4(v[0], v[1], v[2], v[3]);
        *(float4*)(crow + c1) = make_float4(v[4], v[5], v[6], v[7]);
    }
}

__global__ __launch_bounds__(256) void colsum_kernel(
    const float* __restrict__ P, float* __restrict__ sums, int Nn, int Mm, int chunk)
{
    const int g = blockIdx.x * 256 + threadIdx.x;
    const int b = g >> 10;
    const int m = g & 1023;
    const int n0 = blockIdx.y * chunk;
    const float* p = P + (long long)b * Nn * Mm + (long long)n0 * Mm + m;
    float s0 = 0.f, s1 = 0.f, s2 = 0.f, s3 = 0.f;
    for (int n = 0; n < chunk; n += 4) {
        s0 += p[(long long)(n + 0) * Mm];
        s1 += p[(long long)(n + 1) * Mm];
        s2 += p[(long long)(n + 2) * Mm];
        s3 += p[(long long)(n + 3) * Mm];
    }
    atomicAdd(&sums[g], (s0 + s1) + (s2 + s3));
}

__global__ __launch_bounds__(256) void scale_kernel(
    float* __restrict__ P, const float* __restrict__ sums)
{
    const long long base = (blockIdx.x * 256LL + threadIdx.x) * 4;
    const int b = (int)(base >> 20);
    const int col = (int)(base & 1023);
    float4 v = *(float4*)(P + base);
    const float4 s = *(const float4*)(sums + (b << 10) + col);
    v.x /= s.x; v.y /= s.y; v.z /= s.z; v.w /= s.w;
    *(float4*)(P + base) = v;
}

// ---------------------------------------------------------------------------
extern "C" void kernel_launch(void* const* d_in, const int* in_sizes, int n_in,
                              void* d_out, int out_size, void* d_ws, size_t ws_size,
                              hipStream_t stream)
{
    const int B = 8, N = 1024, ME = 1024, D = 1024;
    const float* z = (const float*)d_in[0];   // [B,N,D]
    const float* e = (const float*)d_in[1];   // [B,ME,D]
    const float* M = (const float*)d_in[2];   // [D,D]
    float* out   = (float*)d_out;
    float* e_out = out;                         // [B,N,D]
    float* Aout  = out + (long long)B * N * D;  // [B,N,ME]

    const size_t MB = 1024 * 1024;
    const size_t NEEDED = 100 * MB + (size_t)B * ME * sizeof(float);

    if (ws_size >= NEEDED) {
        char* W = (char*)d_ws;
        __bf16* z_hi  = (__bf16*)(W);             // 16 MB; later: P_bf [B,N,ME]
        __bf16* z_lo  = (__bf16*)(W + 16 * MB);   // 16 MB; later: eTs [B,D,ME]
        __bf16* e_hi  = (__bf16*)(W + 32 * MB);
        __bf16* e_lo  = (__bf16*)(W + 48 * MB);
        __bf16* MT_hi = (__bf16*)(W + 64 * MB);
        __bf16* MT_lo = (__bf16*)(W + 66 * MB);
        __bf16* zM_hi = (__bf16*)(W + 68 * MB);
        __bf16* zM_lo = (__bf16*)(W + 84 * MB);
        float*  sums  = (float*)(W + 100 * MB);
        __bf16* P_bf  = z_hi;   // reused after GEMM1 consumes z
        __bf16* eTs   = z_lo;   // reused after GEMM1 consumes z

        // 1) prep: z/e hi-lo splits, M transpose-split, zero sums.
        prep_kernel<<<dim3(17416), 256, 0, stream>>>(
            z, e, M, z_hi, z_lo, e_hi, e_lo, MT_hi, MT_lo, sums, D);

        // 2) GEMM1: zM = z @ M (NT vs M^T), split in, split bf16 out. [8192x1024x1024]
        mfma_gemm_nt<1, 2><<<dim3(D / 128, (B * N) / 128, 1), 256, 0, stream>>>(
            z_hi, z_lo, MT_hi, MT_lo, nullptr, zM_hi, zM_lo, nullptr, 0, 0, 0, D, D);

        // 3) GEMM2: P = exp(sigmoid(zM @ e^T)) -> bf16 P_bf + fused column sums.
        mfma_gemm_nt<1, 1><<<dim3(ME / 128, N / 128, B), 256, 0, stream>>>(
            zM_hi, zM_lo, e_hi, e_lo, nullptr, P_bf, nullptr, sums,
            (long long)N * D, (long long)ME * D, (long long)N * ME, ME, D);

        // 4) finish: A = P_bf / s (fp32 output), eTs = e^T / s (bf16).
        finish_kernel<<<dim3(10240), 256, 0, stream>>>(
            P_bf, sums, Aout, e, eTs, ME, D);

        // 5) GEMM3: e_out = P_bf @ eTs^T == A @ e (normalization folded into eTs).
        mfma_gemm_nt<0, 0><<<dim3(D / 128, N / 128, B), 256, 0, stream>>>(
            P_bf, nullptr, eTs, nullptr, e_out, nullptr, nullptr, nullptr,
            (long long)N * ME, (long long)D * ME, (long long)N * D, D, ME);
    } else {
        // fp32 fallback (round-1 path), needs 32 MB + 32 KB.
        float* zM   = (float*)d_ws;
        float* sums = (float*)((char*)d_ws + (size_t)B * N * D * 4);
        gemm_kernel<false, 0><<<dim3(ME / TILE, (B * N) / TILE, 1), 256, 0, stream>>>(
            z, M, zM, 0, 0, 0, B * N, D, D);
        gemm_kernel<true, 1><<<dim3(ME / TILE, N / TILE, B), 256, 0, stream>>>(
            zM, e, Aout, (long long)N * D, (long long)ME * D, (long long)N * ME, N, ME, D);
        hipMemsetAsync(sums, 0, (size_t)B * ME * sizeof(float), stream);
        colsum_kernel<<<dim3((B * ME) / 256, 8), 256, 0, stream>>>(Aout, sums, N, ME, N / 8);
        scale_kernel<<<dim3((B * N * ME / 4) / 256), 256, 0, stream>>>(Aout, sums);
        gemm_kernel<false, 0><<<dim3(D / TILE, N / TILE, B), 256, 0, stream>>>(
            Aout, e, e_out, (long long)N * ME, (long long)ME * D, (long long)N * D, N, D, ME);
    }
}

// Round 7
// 258.713 us; speedup vs baseline: 1.1859x; 1.0678x over previous
//
#include <hip/hip_runtime.h>
#include <math.h>
#include <stdint.h>

// Problem: B=8, N=1024, ME=1024, D=1024, fp32 in/out.
// a = sigmoid(z @ M @ e^T); A = softmax(a, axis=N); e_out = A @ e.
// Outputs concatenated: e_out [B,N,D] then A [B,N,ME].
//
// Round 7: round-6 structure with the staging-coverage bug fixed
// (stage_f32_split must run 8 passes of 256 float4s, not 2 — rows 32..127
// were left uninitialized -> NaN).
//  - 4 nodes (prep / gemm1 / gemm2 / gemm3+Ascale)
//  - split-bf16 MFMA for GEMM1/2 (hi*hi + hi*lo + lo*hi, fp32 acc)
//  - fp32 operands converted to hi/lo bf16 *during LDS staging*
//  - 3-bit XOR LDS swizzle (BK=64 = 8 x 16B chunks/row) -> 2-way reads (free)
//  - GEMM3 stages B = e^T * (1/colsum) on the fly; A = P/s extra grid slice.

typedef __bf16 bf16_8 __attribute__((ext_vector_type(8)));
typedef __bf16 bf16_4 __attribute__((ext_vector_type(4)));
typedef float  f32_4  __attribute__((ext_vector_type(4)));

// ---------------------------------------------------------------------------
__device__ __forceinline__ void gload_lds16(const __bf16* g, __bf16* l) {
    __builtin_amdgcn_global_load_lds(
        (const __attribute__((address_space(1))) void*)g,
        (__attribute__((address_space(3))) void*)l, 16, 0, 0);
}

__device__ __forceinline__ int swz8(int r) { return (r ^ (r >> 2)) & 7; }

// Stage a 128x64 bf16 tile via global_load_lds. Row r, LDS slot s holds global
// 16B-chunk s ^ swz8(r). 1024 chunks = 4 x 256 threads.
__device__ __forceinline__ void stage_bf16(const __bf16* __restrict__ g, int ldK,
                                           int k0, __bf16* lds, int tid) {
#pragma unroll
    for (int t = 0; t < 4; ++t) {
        const int c = t * 256 + tid;
        const int row = c >> 3, slot = c & 7;
        gload_lds16(g + (long long)row * ldK + k0 + (slot ^ swz8(row)) * 8,
                    lds + (t * 256 + (tid >> 6) * 64) * 8);
    }
}

// Stage a 128x64 tile from an fp32 source, split to hi/lo bf16 (no transpose).
// 128 rows x 16 float4/row = 2048 float4 = 8 passes x 256 threads.
__device__ __forceinline__ void stage_f32_split(const float* __restrict__ g, int ldK,
                                                int k0, __bf16* sH, __bf16* sL, int tid) {
#pragma unroll
    for (int p = 0; p < 8; ++p) {
        const int qi = p * 256 + tid;
        const int row = qi >> 4, kq4 = qi & 15;
        const float4 v = *(const float4*)(g + (long long)row * ldK + k0 + kq4 * 4);
        const int off = row * 64 + (((kq4 >> 1) ^ swz8(row)) * 8) + (kq4 & 1) * 4;
        bf16_4 h, l;
        h[0] = (__bf16)v.x; l[0] = (__bf16)(v.x - (float)h[0]);
        h[1] = (__bf16)v.y; l[1] = (__bf16)(v.y - (float)h[1]);
        h[2] = (__bf16)v.z; l[2] = (__bf16)(v.z - (float)h[2]);
        h[3] = (__bf16)v.w; l[3] = (__bf16)(v.w - (float)h[3]);
        *(bf16_4*)(sH + off) = h;
        *(bf16_4*)(sL + off) = l;
    }
}

// Fragment LDS offset (bf16 units): row r, k-chunk cK (0..7).
__device__ __forceinline__ int frag_off(int r, int cK) {
    return r * 64 + ((cK ^ swz8(r)) * 8);
}

// ---------------------------------------------------------------------------
// GEMM1: zM = z @ M (via M^T, NT). A = z fp32 self-staged split; B = MT hi/lo.
// Out: zM hi/lo bf16. Grid (8 colblk, 64 rowblk).
__global__ __launch_bounds__(256) void gemm1_kernel(
    const float* __restrict__ z,
    const __bf16* __restrict__ MT_hi, const __bf16* __restrict__ MT_lo,
    __bf16* __restrict__ zM_hi, __bf16* __restrict__ zM_lo)
{
    const int D = 1024;
    __shared__ __bf16 sAh[8192], sAl[8192], sBh[8192], sBl[8192];
    const int tid = threadIdx.x, lane = tid & 63, w = tid >> 6;
    const int fr = lane & 15, q = lane >> 4;
    const int wr = (w >> 1) * 64, wc = (w & 1) * 64;

    const float*  pA  = z     + (long long)blockIdx.y * 128 * D;
    const __bf16* pBh = MT_hi + (long long)blockIdx.x * 128 * D;
    const __bf16* pBl = MT_lo + (long long)blockIdx.x * 128 * D;

    f32_4 acc[4][4];
#pragma unroll
    for (int i = 0; i < 4; ++i)
#pragma unroll
        for (int j = 0; j < 4; ++j) acc[i][j] = (f32_4){0.f, 0.f, 0.f, 0.f};

    for (int k0 = 0; k0 < D; k0 += 64) {
        stage_bf16(pBh, D, k0, sBh, tid);           // DMA first...
        stage_bf16(pBl, D, k0, sBl, tid);
        stage_f32_split(pA, D, k0, sAh, sAl, tid);  // ...VALU staging overlaps
        __syncthreads();
#pragma unroll
        for (int ch = 0; ch < 2; ++ch) {
            bf16_8 ah[4], al[4], bh[4], bl[4];
#pragma unroll
            for (int i = 0; i < 4; ++i) {
                const int oA = frag_off(wr + 16 * i + fr, ch * 4 + q);
                ah[i] = *(const bf16_8*)(sAh + oA);
                al[i] = *(const bf16_8*)(sAl + oA);
                const int oB = frag_off(wc + 16 * i + fr, ch * 4 + q);
                bh[i] = *(const bf16_8*)(sBh + oB);
                bl[i] = *(const bf16_8*)(sBl + oB);
            }
#pragma unroll
            for (int i = 0; i < 4; ++i)
#pragma unroll
                for (int j = 0; j < 4; ++j) {
                    acc[i][j] = __builtin_amdgcn_mfma_f32_16x16x32_bf16(ah[i], bh[j], acc[i][j], 0, 0, 0);
                    acc[i][j] = __builtin_amdgcn_mfma_f32_16x16x32_bf16(ah[i], bl[j], acc[i][j], 0, 0, 0);
                    acc[i][j] = __builtin_amdgcn_mfma_f32_16x16x32_bf16(al[i], bh[j], acc[i][j], 0, 0, 0);
                }
        }
        __syncthreads();
    }

    const int row0 = blockIdx.y * 128 + wr;
    const int col0 = blockIdx.x * 128 + wc;
#pragma unroll
    for (int i = 0; i < 4; ++i)
#pragma unroll
        for (int j = 0; j < 4; ++j) {
            const int col = col0 + 16 * j + fr;
#pragma unroll
            for (int reg = 0; reg < 4; ++reg) {
                const int row = row0 + 16 * i + q * 4 + reg;
                const float v = acc[i][j][reg];
                const long long idx = (long long)row * D + col;
                const __bf16 h = (__bf16)v;
                zM_hi[idx] = h;
                zM_lo[idx] = (__bf16)(v - (float)h);
            }
        }
}

// ---------------------------------------------------------------------------
// GEMM2: P = exp(sigmoid(zM @ e^T)) per batch (NT), bf16 out + colsum atomics.
// A = zM hi/lo via DMA; B = e fp32 self-staged split.
// Grid (8,8,8), batch = blockIdx.x (XCD locality).
__global__ __launch_bounds__(256) void gemm2_kernel(
    const __bf16* __restrict__ zM_hi, const __bf16* __restrict__ zM_lo,
    const float* __restrict__ e,
    __bf16* __restrict__ P_bf, float* __restrict__ sums)
{
    const int D = 1024, N = 1024, ME = 1024;
    __shared__ __bf16 sAh[8192], sAl[8192], sBh[8192], sBl[8192];
    const int tid = threadIdx.x, lane = tid & 63, w = tid >> 6;
    const int fr = lane & 15, q = lane >> 4;
    const int wr = (w >> 1) * 64, wc = (w & 1) * 64;
    const int bz = blockIdx.x, rowb = blockIdx.y, colb = blockIdx.z;

    const __bf16* pAh = zM_hi + ((long long)bz * N + rowb * 128) * D;
    const __bf16* pAl = zM_lo + ((long long)bz * N + rowb * 128) * D;
    const float*  pB  = e     + ((long long)bz * ME + colb * 128) * D;

    f32_4 acc[4][4];
#pragma unroll
    for (int i = 0; i < 4; ++i)
#pragma unroll
        for (int j = 0; j < 4; ++j) acc[i][j] = (f32_4){0.f, 0.f, 0.f, 0.f};

    for (int k0 = 0; k0 < D; k0 += 64) {
        stage_bf16(pAh, D, k0, sAh, tid);
        stage_bf16(pAl, D, k0, sAl, tid);
        stage_f32_split(pB, D, k0, sBh, sBl, tid);
        __syncthreads();
#pragma unroll
        for (int ch = 0; ch < 2; ++ch) {
            bf16_8 ah[4], al[4], bh[4], bl[4];
#pragma unroll
            for (int i = 0; i < 4; ++i) {
                const int oA = frag_off(wr + 16 * i + fr, ch * 4 + q);
                ah[i] = *(const bf16_8*)(sAh + oA);
                al[i] = *(const bf16_8*)(sAl + oA);
                const int oB = frag_off(wc + 16 * i + fr, ch * 4 + q);
                bh[i] = *(const bf16_8*)(sBh + oB);
                bl[i] = *(const bf16_8*)(sBl + oB);
            }
#pragma unroll
            for (int i = 0; i < 4; ++i)
#pragma unroll
                for (int j = 0; j < 4; ++j) {
                    acc[i][j] = __builtin_amdgcn_mfma_f32_16x16x32_bf16(ah[i], bh[j], acc[i][j], 0, 0, 0);
                    acc[i][j] = __builtin_amdgcn_mfma_f32_16x16x32_bf16(ah[i], bl[j], acc[i][j], 0, 0, 0);
                    acc[i][j] = __builtin_amdgcn_mfma_f32_16x16x32_bf16(al[i], bh[j], acc[i][j], 0, 0, 0);
                }
        }
        __syncthreads();
    }

    const int row0 = rowb * 128 + wr;
    const int col0 = colb * 128 + wc;
    float cs[4] = {0.f, 0.f, 0.f, 0.f};
#pragma unroll
    for (int i = 0; i < 4; ++i)
#pragma unroll
        for (int j = 0; j < 4; ++j) {
            const int col = col0 + 16 * j + fr;
#pragma unroll
            for (int reg = 0; reg < 4; ++reg) {
                const int row = row0 + 16 * i + q * 4 + reg;
                float v = acc[i][j][reg];
                const float s = 1.0f / (1.0f + __expf(-v));
                v = __expf(s);
                P_bf[(long long)bz * N * ME + (long long)row * ME + col] = (__bf16)v;
                cs[j] += v;
            }
        }
#pragma unroll
    for (int j = 0; j < 4; ++j) {
        float s = cs[j];
        s += __shfl_xor(s, 16, 64);
        s += __shfl_xor(s, 32, 64);
        if (lane < 16)
            atomicAdd(&sums[bz * ME + col0 + 16 * j + lane], s);
    }
}

// ---------------------------------------------------------------------------
// GEMM3': e_out = P @ (e / colsum)  (== A @ e), plus A = P/s output slice.
// A-op = P_bf via DMA; B-op staged from fp32 e with fused transpose + scale.
// Grid (8, 8, 9): z<8 GEMM (batch = x), z==8 A-scale slice.
__global__ __launch_bounds__(256) void gemm3_kernel(
    const __bf16* __restrict__ P_bf, const float* __restrict__ e,
    const float* __restrict__ sums,
    float* __restrict__ e_out, float* __restrict__ Aout)
{
    const int D = 1024, N = 1024, ME = 1024;
    const int tid = threadIdx.x;

    if (blockIdx.z == 8) {   // A = P_bf / s
        const int b = blockIdx.x, yb = blockIdx.y;
        const long long base = ((long long)b * N + yb * 128) * ME;
        const float4 sv = *(const float4*)(sums + b * ME + tid * 4);
        const float4 rs = make_float4(1.f / sv.x, 1.f / sv.y, 1.f / sv.z, 1.f / sv.w);
        for (int it = 0; it < 128; ++it) {
            const long long o = base + (long long)it * ME + tid * 4;
            bf16_4 p = *(const bf16_4*)(P_bf + o);
            *(float4*)(Aout + o) =
                make_float4((float)p[0] * rs.x, (float)p[1] * rs.y,
                            (float)p[2] * rs.z, (float)p[3] * rs.w);
        }
        return;
    }

    __shared__ __bf16 sA[8192], sB[8192];
    __shared__ float rsm[1024];
    const int lane = tid & 63, w = tid >> 6;
    const int fr = lane & 15, q = lane >> 4;
    const int wr = (w >> 1) * 64, wc = (w & 1) * 64;
    const int bz = blockIdx.x, rowb = blockIdx.y, colb = blockIdx.z;

    for (int i = tid; i < 1024; i += 256) rsm[i] = 1.0f / sums[bz * ME + i];

    const __bf16* pA = P_bf + ((long long)bz * N + rowb * 128) * ME;
    const float*  eb = e + (long long)bz * ME * D;
    const int d0 = colb * 128;

    f32_4 acc[4][4];
#pragma unroll
    for (int i = 0; i < 4; ++i)
#pragma unroll
        for (int j = 0; j < 4; ++j) acc[i][j] = (f32_4){0.f, 0.f, 0.f, 0.f};

    __syncthreads();   // rsm ready

    for (int k0 = 0; k0 < ME; k0 += 64) {
        stage_bf16(pA, ME, k0, sA, tid);
        // B tile [128 d x 64 m] = e[m][d] * rsm[m], register 4x4 transpose.
#pragma unroll
        for (int p = 0; p < 2; ++p) {
            const int qi = p * 256 + tid;
            const int m4i = qi >> 5, d4i = qi & 31;
            const int mg = k0 + m4i * 4;
            float rv[4][4];
            float sm[4];
#pragma unroll
            for (int jm = 0; jm < 4; ++jm) {
                *(float4*)rv[jm] = *(const float4*)(eb + (long long)(mg + jm) * D + d0 + d4i * 4);
                sm[jm] = rsm[mg + jm];
            }
#pragma unroll
            for (int jd = 0; jd < 4; ++jd) {
                const int d = d4i * 4 + jd;
                bf16_4 o;
                o[0] = (__bf16)(rv[0][jd] * sm[0]);
                o[1] = (__bf16)(rv[1][jd] * sm[1]);
                o[2] = (__bf16)(rv[2][jd] * sm[2]);
                o[3] = (__bf16)(rv[3][jd] * sm[3]);
                const int off = d * 64 + (((m4i >> 1) ^ swz8(d)) * 8) + (m4i & 1) * 4;
                *(bf16_4*)(sB + off) = o;
            }
        }
        __syncthreads();
#pragma unroll
        for (int ch = 0; ch < 2; ++ch) {
            bf16_8 ah[4], bh[4];
#pragma unroll
            for (int i = 0; i < 4; ++i) {
                ah[i] = *(const bf16_8*)(sA + frag_off(wr + 16 * i + fr, ch * 4 + q));
                bh[i] = *(const bf16_8*)(sB + frag_off(wc + 16 * i + fr, ch * 4 + q));
            }
#pragma unroll
            for (int i = 0; i < 4; ++i)
#pragma unroll
                for (int j = 0; j < 4; ++j)
                    acc[i][j] = __builtin_amdgcn_mfma_f32_16x16x32_bf16(ah[i], bh[j], acc[i][j], 0, 0, 0);
        }
        __syncthreads();
    }

    const int row0 = rowb * 128 + wr;
    const int col0 = d0 + wc;
#pragma unroll
    for (int i = 0; i < 4; ++i)
#pragma unroll
        for (int j = 0; j < 4; ++j) {
            const int col = col0 + 16 * j + fr;
#pragma unroll
            for (int reg = 0; reg < 4; ++reg) {
                const int row = row0 + 16 * i + q * 4 + reg;
                e_out[(long long)bz * N * D + (long long)row * D + col] = acc[i][j][reg];
            }
        }
}

// ---------------------------------------------------------------------------
// prep: M transpose-split (1024 blocks) + zero sums (8 blocks).
__global__ __launch_bounds__(256) void prep_kernel(
    const float* __restrict__ M,
    __bf16* __restrict__ MT_hi, __bf16* __restrict__ MT_lo,
    float* __restrict__ sums, int D)
{
    __shared__ float t32[32][33];
    const int bid = blockIdx.x, tid = threadIdx.x;
    if (bid < 1024) {
        const int r0 = (bid >> 5) * 32, c0 = (bid & 31) * 32;
        const int tx = tid & 31, ty = tid >> 5;
#pragma unroll
        for (int rr = ty; rr < 32; rr += 8)
            t32[rr][tx] = M[(long long)(r0 + rr) * D + c0 + tx];
        __syncthreads();
#pragma unroll
        for (int cc = ty; cc < 32; cc += 8) {
            const float v = t32[tx][cc];
            const long long o = (long long)(c0 + cc) * D + r0 + tx;
            const __bf16 h = (__bf16)v;
            MT_hi[o] = h;
            MT_lo[o] = (__bf16)(v - (float)h);
        }
    } else {
        const int i = ((bid - 1024) * 256 + tid) * 4;
        *(float4*)(sums + i) = make_float4(0.f, 0.f, 0.f, 0.f);
    }
}

// ---------------------------------------------------------------------------
// Fallback fp32 path (round-1 kernels).
#define TILE 128
#define KT 8
template<bool BT, int EPI>
__global__ __launch_bounds__(256) void gemm_kernel(
    const float* __restrict__ A, const float* __restrict__ B, float* __restrict__ C,
    long long sA, long long sB, long long sC, int Mrows, int Ncols, int K)
{
    __shared__ float As[KT][TILE + 4];
    __shared__ float Bs[KT][TILE + 4];
    const int bz = blockIdx.z;
    A += (long long)bz * sA; B += (long long)bz * sB; C += (long long)bz * sC;
    const int tid = threadIdx.x;
    const int row0 = blockIdx.y * TILE, col0 = blockIdx.x * TILE;
    const int ld_r = tid >> 1, ld_k4 = (tid & 1) * 4;
    const int bn_k = tid >> 5, bn_c4 = (tid & 31) * 4;
    const int tx = tid & 15, ty = tid >> 4;
    const int c0 = tx * 4, c1 = c0 + 64, r0 = ty * 4, r1 = r0 + 64;
    float acc[8][8];
#pragma unroll
    for (int i = 0; i < 8; i++)
#pragma unroll
        for (int j = 0; j < 8; j++) acc[i][j] = 0.f;
    for (int k0 = 0; k0 < K; k0 += KT) {
        float4 av = *(const float4*)(A + (long long)(row0 + ld_r) * K + k0 + ld_k4);
        float4 bv;
        if (BT) bv = *(const float4*)(B + (long long)(col0 + ld_r) * K + k0 + ld_k4);
        else    bv = *(const float4*)(B + (long long)(k0 + bn_k) * Ncols + col0 + bn_c4);
        __syncthreads();
        As[ld_k4 + 0][ld_r] = av.x; As[ld_k4 + 1][ld_r] = av.y;
        As[ld_k4 + 2][ld_r] = av.z; As[ld_k4 + 3][ld_r] = av.w;
        if (BT) {
            Bs[ld_k4 + 0][ld_r] = bv.x; Bs[ld_k4 + 1][ld_r] = bv.y;
            Bs[ld_k4 + 2][ld_r] = bv.z; Bs[ld_k4 + 3][ld_r] = bv.w;
        } else {
            *(float4*)&Bs[bn_k][bn_c4] = bv;
        }
        __syncthreads();
#pragma unroll
        for (int kk = 0; kk < KT; kk++) {
            float4 a0 = *(const float4*)&As[kk][r0];
            float4 a1 = *(const float4*)&As[kk][r1];
            float4 b0 = *(const float4*)&Bs[kk][c0];
            float4 b1 = *(const float4*)&Bs[kk][c1];
            float ar[8] = {a0.x, a0.y, a0.z, a0.w, a1.x, a1.y, a1.z, a1.w};
            float br[8] = {b0.x, b0.y, b0.z, b0.w, b1.x, b1.y, b1.z, b1.w};
#pragma unroll
            for (int i = 0; i < 8; i++)
#pragma unroll
                for (int j = 0; j < 8; j++) acc[i][j] += ar[i] * br[j];
        }
    }
#pragma unroll
    for (int i = 0; i < 8; i++) {
        const int rr = (i < 4) ? (r0 + i) : (r1 + i - 4);
        float* crow = C + (long long)(row0 + rr) * Ncols + col0;
        float v[8];
#pragma unroll
        for (int j = 0; j < 8; j++) v[j] = acc[i][j];
        if (EPI == 1) {
#pragma unroll
            for (int j = 0; j < 8; j++) {
                float s = 1.0f / (1.0f + __expf(-v[j]));
                v[j] = __expf(s);
            }
        }
        *(float4*)(crow + c0) = make_float4(v[0], v[1], v[2], v[3]);
        *(float4*)(crow + c1) = make_float4(v[4], v[5], v[6], v[7]);
    }
}

__global__ __launch_bounds__(256) void colsum_kernel(
    const float* __restrict__ P, float* __restrict__ sums, int Nn, int Mm, int chunk)
{
    const int g = blockIdx.x * 256 + threadIdx.x;
    const int b = g >> 10;
    const int m = g & 1023;
    const int n0 = blockIdx.y * chunk;
    const float* p = P + (long long)b * Nn * Mm + (long long)n0 * Mm + m;
    float s0 = 0.f, s1 = 0.f, s2 = 0.f, s3 = 0.f;
    for (int n = 0; n < chunk; n += 4) {
        s0 += p[(long long)(n + 0) * Mm];
        s1 += p[(long long)(n + 1) * Mm];
        s2 += p[(long long)(n + 2) * Mm];
        s3 += p[(long long)(n + 3) * Mm];
    }
    atomicAdd(&sums[g], (s0 + s1) + (s2 + s3));
}

__global__ __launch_bounds__(256) void scale_kernel(
    float* __restrict__ P, const float* __restrict__ sums)
{
    const long long base = (blockIdx.x * 256LL + threadIdx.x) * 4;
    const int b = (int)(base >> 20);
    const int col = (int)(base & 1023);
    float4 v = *(float4*)(P + base);
    const float4 s = *(const float4*)(sums + (b << 10) + col);
    v.x /= s.x; v.y /= s.y; v.z /= s.z; v.w /= s.w;
    *(float4*)(P + base) = v;
}

// ---------------------------------------------------------------------------
extern "C" void kernel_launch(void* const* d_in, const int* in_sizes, int n_in,
                              void* d_out, int out_size, void* d_ws, size_t ws_size,
                              hipStream_t stream)
{
    const int B = 8, N = 1024, ME = 1024, D = 1024;
    const float* z = (const float*)d_in[0];   // [B,N,D]
    const float* e = (const float*)d_in[1];   // [B,ME,D]
    const float* M = (const float*)d_in[2];   // [D,D]
    float* out   = (float*)d_out;
    float* e_out = out;                         // [B,N,D]
    float* Aout  = out + (long long)B * N * D;  // [B,N,ME]

    const size_t MB = 1024 * 1024;
    const size_t NEEDED = 52 * MB + (size_t)B * ME * sizeof(float);

    if (ws_size >= NEEDED) {
        char* W = (char*)d_ws;
        __bf16* MT_hi = (__bf16*)(W);             // 2 MB
        __bf16* MT_lo = (__bf16*)(W + 2 * MB);    // 2 MB
        __bf16* zM_hi = (__bf16*)(W + 4 * MB);    // 16 MB
        __bf16* zM_lo = (__bf16*)(W + 20 * MB);   // 16 MB
        __bf16* P_bf  = (__bf16*)(W + 36 * MB);   // 16 MB
        float*  sums  = (float*)(W + 52 * MB);    // 32 KB

        // 1) prep: M^T hi/lo + zero sums.
        prep_kernel<<<dim3(1032), 256, 0, stream>>>(M, MT_hi, MT_lo, sums, D);

        // 2) GEMM1: zM = z @ M (z self-staged from fp32).
        gemm1_kernel<<<dim3(8, 64, 1), 256, 0, stream>>>(z, MT_hi, MT_lo, zM_hi, zM_lo);

        // 3) GEMM2: P = exp(sigmoid(zM @ e^T)) -> bf16 + colsum atomics.
        gemm2_kernel<<<dim3(8, 8, 8), 256, 0, stream>>>(zM_hi, zM_lo, e, P_bf, sums);

        // 4) GEMM3': e_out = P @ (e/s); A = P/s via extra grid slice.
        gemm3_kernel<<<dim3(8, 8, 9), 256, 0, stream>>>(P_bf, e, sums, e_out, Aout);
    } else {
        // fp32 fallback (round-1 path), needs 32 MB + 32 KB.
        float* zM   = (float*)d_ws;
        float* sums = (float*)((char*)d_ws + (size_t)B * N * D * 4);
        gemm_kernel<false, 0><<<dim3(ME / TILE, (B * N) / TILE, 1), 256, 0, stream>>>(
            z, M, zM, 0, 0, 0, B * N, D, D);
        gemm_kernel<true, 1><<<dim3(ME / TILE, N / TILE, B), 256, 0, stream>>>(
            zM, e, Aout, (long long)N * D, (long long)ME * D, (long long)N * ME, N, ME, D);
        hipMemsetAsync(sums, 0, (size_t)B * ME * sizeof(float), stream);
        colsum_kernel<<<dim3((B * ME) / 256, 8), 256, 0, stream>>>(Aout, sums, N, ME, N / 8);
        scale_kernel<<<dim3((B * N * ME / 4) / 256), 256, 0, stream>>>(Aout, sums);
        gemm_kernel<false, 0><<<dim3(D / TILE, N / TILE, B), 256, 0, stream>>>(
            Aout, e, e_out, (long long)N * ME, (long long)ME * D, (long long)N * D, N, D, ME);
    }
}